// Round 2
// baseline (313.320 us; speedup 1.0000x reference)
//
#include <hip/hip_runtime.h>
#include <hip/hip_bf16.h>

#define NR   8192
#define CIN  200
#define CNN  128
#define NCH  32
#define JC   (NR / NCH)   // 256
#define BN_EPS 1e-5f

// ws layout (floats)
#define OFF_SCALE 0
#define OFF_SHIFT 256
#define OFF_V     512
#define OFF_S     (OFF_V + NR * CNN)
#define OFF_DTH   (OFF_S + NR * CNN)
#define OFF_V2    (OFF_DTH + NR * CNN)
#define OFF_PART  (OFF_V2 + NR * 8)

// ---------------------------------------------------------------- BN stats
__global__ __launch_bounds__(256) void bn_stats_k(
    const float* __restrict__ H, const float* __restrict__ gamma,
    const float* __restrict__ beta, float* __restrict__ ws)
{
    const int c = blockIdx.x;
    const int t = threadIdx.x;
    float sum = 0.f, sq = 0.f;
    for (int r = t; r < NR; r += 256) {
        float v = H[(size_t)r * CIN + c];
        sum += v; sq += v * v;
    }
    #pragma unroll
    for (int off = 32; off >= 1; off >>= 1) {
        sum += __shfl_down(sum, off);
        sq  += __shfl_down(sq, off);
    }
    __shared__ float s0[4], s1[4];
    const int wid = t >> 6, lane = t & 63;
    if (lane == 0) { s0[wid] = sum; s1[wid] = sq; }
    __syncthreads();
    if (t == 0) {
        sum = s0[0] + s0[1] + s0[2] + s0[3];
        sq  = s1[0] + s1[1] + s1[2] + s1[3];
        float mu   = sum / (float)NR;
        float var  = sq / (float)NR - mu * mu;
        float rstd = rsqrtf(var + BN_EPS);
        float sc   = rstd * gamma[c];
        ws[OFF_SCALE + c] = sc;
        ws[OFF_SHIFT + c] = beta[c] - mu * sc;
    }
}

// ------------------------------------------- fused BN + (V | DTH) dual GEMM
// M=8192, Ntot=256 (n<128 -> V=relu(.+b1), else DTH=.+bdt), K=200
__global__ __launch_bounds__(256) void gemm_bn_k(
    const float* __restrict__ H, const float* __restrict__ w1,
    const float* __restrict__ b1, const float* __restrict__ wdt,
    const float* __restrict__ bdt, const float* __restrict__ ws,
    float* __restrict__ V, float* __restrict__ DTH)
{
    __shared__ float As[8][68];
    __shared__ float Bs[8][68];
    const int t  = threadIdx.x;
    const int m0 = blockIdx.x * 64;
    const int n0 = blockIdx.y * 64;
    const int tx = t & 15, ty = t >> 4;
    const int lm = t >> 2;          // 0..63
    const int lk = (t & 3) * 2;     // 0,2,4,6
    const float* scale = ws + OFF_SCALE;
    const float* shift = ws + OFF_SHIFT;
    const int gn = n0 + lm;
    const float* brow = (gn < CNN) ? (w1 + (size_t)gn * CIN)
                                   : (wdt + (size_t)(gn - CNN) * CIN);
    float acc[4][4] = {};
    for (int k0 = 0; k0 < CIN; k0 += 8) {
        float2 ha = *(const float2*)(H + (size_t)(m0 + lm) * CIN + k0 + lk);
        float2 hb = *(const float2*)(brow + k0 + lk);
        float sc0 = scale[k0 + lk], sc1 = scale[k0 + lk + 1];
        float sh0 = shift[k0 + lk], sh1 = shift[k0 + lk + 1];
        __syncthreads();
        As[lk][lm]     = ha.x * sc0 + sh0;
        As[lk + 1][lm] = ha.y * sc1 + sh1;
        Bs[lk][lm]     = hb.x;
        Bs[lk + 1][lm] = hb.y;
        __syncthreads();
        #pragma unroll
        for (int kk = 0; kk < 8; ++kk) {
            float a[4], b[4];
            #pragma unroll
            for (int i = 0; i < 4; ++i) a[i] = As[kk][ty * 4 + i];
            #pragma unroll
            for (int j = 0; j < 4; ++j) b[j] = Bs[kk][tx * 4 + j];
            #pragma unroll
            for (int i = 0; i < 4; ++i)
                #pragma unroll
                for (int j = 0; j < 4; ++j)
                    acc[i][j] += a[i] * b[j];
        }
    }
    #pragma unroll
    for (int i = 0; i < 4; ++i) {
        int m = m0 + ty * 4 + i;
        #pragma unroll
        for (int j = 0; j < 4; ++j) {
            int n = n0 + tx * 4 + j;
            float v = acc[i][j];
            if (n < CNN) V[(size_t)m * CNN + n] = fmaxf(v + b1[n], 0.f);
            else         DTH[(size_t)m * CNN + (n - CNN)] = v + bdt[n - CNN];
        }
    }
}

// ------------------------------------------------- iterate GEMM (V update)
// V = relu((DTH + alpha*S) @ wdtd^T + bdtd), M=8192, N=128, K=128
__global__ __launch_bounds__(256) void gemm_iter_k(
    const float* __restrict__ DTH, const float* __restrict__ S,
    const float* __restrict__ alpha_p, const float* __restrict__ wdtd,
    const float* __restrict__ bdtd, float* __restrict__ V,
    float* __restrict__ outV)
{
    __shared__ float As[8][68];
    __shared__ float Bs[8][68];
    const int t  = threadIdx.x;
    const int m0 = blockIdx.x * 64;
    const int n0 = blockIdx.y * 64;
    const int tx = t & 15, ty = t >> 4;
    const int lm = t >> 2;
    const int lk = (t & 3) * 2;
    const float alpha = alpha_p[0];
    const float* brow = wdtd + (size_t)(n0 + lm) * CNN;
    float acc[4][4] = {};
    for (int k0 = 0; k0 < CNN; k0 += 8) {
        float2 d = *(const float2*)(DTH + (size_t)(m0 + lm) * CNN + k0 + lk);
        float2 s = *(const float2*)(S   + (size_t)(m0 + lm) * CNN + k0 + lk);
        float2 w = *(const float2*)(brow + k0 + lk);
        __syncthreads();
        As[lk][lm]     = d.x + alpha * s.x;
        As[lk + 1][lm] = d.y + alpha * s.y;
        Bs[lk][lm]     = w.x;
        Bs[lk + 1][lm] = w.y;
        __syncthreads();
        #pragma unroll
        for (int kk = 0; kk < 8; ++kk) {
            float a[4], b[4];
            #pragma unroll
            for (int i = 0; i < 4; ++i) a[i] = As[kk][ty * 4 + i];
            #pragma unroll
            for (int j = 0; j < 4; ++j) b[j] = Bs[kk][tx * 4 + j];
            #pragma unroll
            for (int i = 0; i < 4; ++i)
                #pragma unroll
                for (int j = 0; j < 4; ++j)
                    acc[i][j] += a[i] * b[j];
        }
    }
    #pragma unroll
    for (int i = 0; i < 4; ++i) {
        int m = m0 + ty * 4 + i;
        #pragma unroll
        for (int j = 0; j < 4; ++j) {
            int n = n0 + tx * 4 + j;
            float v = fmaxf(acc[i][j] + bdtd[n], 0.f);
            V[(size_t)m * CNN + n] = v;
            if (outV) outV[(size_t)m * CNN + n] = v;
        }
    }
}

// ------------------------------------------------------ H_R = V @ wdt (f32)
// M=8192, N=200, K=128; B = wdt laid out [K][N]
__global__ __launch_bounds__(256) void gemm_hr_k(
    const float* __restrict__ Vf, const float* __restrict__ wdt,
    float* __restrict__ out)
{
    __shared__ float As[8][68];
    __shared__ float Bs[8][68];
    const int t  = threadIdx.x;
    const int m0 = blockIdx.x * 64;
    const int n0 = blockIdx.y * 64;
    const int tx = t & 15, ty = t >> 4;
    const int lm = t >> 2;
    const int lk = (t & 3) * 2;
    const int bkk = t >> 5;          // 0..7
    const int bnn = (t & 31) * 2;    // 0..62
    float acc[4][4] = {};
    for (int k0 = 0; k0 < CNN; k0 += 8) {
        float2 a2 = *(const float2*)(Vf + (size_t)(m0 + lm) * CNN + k0 + lk);
        float2 w2 = make_float2(0.f, 0.f);
        if (n0 + bnn < CIN)
            w2 = *(const float2*)(wdt + (size_t)(k0 + bkk) * CIN + n0 + bnn);
        __syncthreads();
        As[lk][lm]     = a2.x;
        As[lk + 1][lm] = a2.y;
        Bs[bkk][bnn]     = w2.x;
        Bs[bkk][bnn + 1] = w2.y;
        __syncthreads();
        #pragma unroll
        for (int kk = 0; kk < 8; ++kk) {
            float a[4], b[4];
            #pragma unroll
            for (int i = 0; i < 4; ++i) a[i] = As[kk][ty * 4 + i];
            #pragma unroll
            for (int j = 0; j < 4; ++j) b[j] = Bs[kk][tx * 4 + j];
            #pragma unroll
            for (int i = 0; i < 4; ++i)
                #pragma unroll
                for (int j = 0; j < 4; ++j)
                    acc[i][j] += a[i] * b[j];
        }
    }
    #pragma unroll
    for (int i = 0; i < 4; ++i) {
        int m = m0 + ty * 4 + i;
        #pragma unroll
        for (int j = 0; j < 4; ++j) {
            int n = n0 + tx * 4 + j;
            if (n < CIN) out[(size_t)m * CIN + n] = acc[i][j];
        }
    }
}

// --------------------------------------- aenet layers 1+2: V -> V2 (padded 8)
__global__ __launch_bounds__(256) void aenet_l12_k(
    const float* __restrict__ V, const float* __restrict__ aw1,
    const float* __restrict__ ab1, const float* __restrict__ aw2,
    const float* __restrict__ ab2, float* __restrict__ V2)
{
    __shared__ float w1s[10 * 128];
    __shared__ float b1s[10];
    __shared__ float w2s[50];
    __shared__ float b2s[5];
    const int t = threadIdx.x;
    for (int i = t; i < 1280; i += 256) w1s[i] = aw1[i];
    if (t < 10) b1s[t] = ab1[t];
    if (t < 50) w2s[t] = aw2[t];
    if (t < 5)  b2s[t] = ab2[t];
    __syncthreads();
    const int r = blockIdx.x * 256 + t;
    const float4* vrow = (const float4*)(V + (size_t)r * CNN);
    float acc[10];
    #pragma unroll
    for (int o = 0; o < 10; ++o) acc[o] = b1s[o];
    const float4* w1v = (const float4*)w1s;
    for (int kc = 0; kc < 32; ++kc) {
        float4 v = vrow[kc];
        #pragma unroll
        for (int o = 0; o < 10; ++o) {
            float4 w = w1v[o * 32 + kc];
            acc[o] += v.x * w.x + v.y * w.y + v.z * w.z + v.w * w.w;
        }
    }
    float v1[10];
    #pragma unroll
    for (int o = 0; o < 10; ++o) v1[o] = fmaxf(acc[o], 0.f);
    float v2[5];
    #pragma unroll
    for (int p = 0; p < 5; ++p) {
        float s = b2s[p];
        #pragma unroll
        for (int o = 0; o < 10; ++o) s += w2s[p * 10 + o] * v1[o];
        v2[p] = fmaxf(s, 0.f);
    }
    float4 lo = make_float4(v2[0], v2[1], v2[2], v2[3]);
    float4 hi = make_float4(v2[4], 0.f, 0.f, 0.f);
    *(float4*)(V2 + (size_t)r * 8)     = lo;
    *(float4*)(V2 + (size_t)r * 8 + 4) = hi;
}

// ---------------------------------------- attention partials (no max shift:
// scores are O(1e-2) by construction — exp cannot overflow; partials add)
__global__ __launch_bounds__(256) void attn_partial_k(
    const float* __restrict__ V2, float* __restrict__ part)
{
    __shared__ float Ks[JC][8];
    const int t  = threadIdx.x;
    const int j0 = blockIdx.x * JC;
    {
        const float4* src = (const float4*)(V2 + (size_t)j0 * 8);
        float4* dst = (float4*)&Ks[0][0];
        #pragma unroll
        for (int i = 0; i < (JC * 2) / 256; ++i)
            dst[t + i * 256] = src[t + i * 256];
    }
    __syncthreads();
    const int r0 = blockIdx.y * 512 + t;
    const int r1 = r0 + 256;
    float q0[5], q1[5];
    #pragma unroll
    for (int c = 0; c < 5; ++c) {
        q0[c] = V2[(size_t)r0 * 8 + c];
        q1[c] = V2[(size_t)r1 * 8 + c];
    }
    float l0 = 0.f, l1 = 0.f;
    float a0[5] = {0, 0, 0, 0, 0}, a1[5] = {0, 0, 0, 0, 0};
    #pragma unroll 4
    for (int jj = 0; jj < JC; ++jj) {
        float4 k4 = *(const float4*)&Ks[jj][0];
        float  k5 = Ks[jj][4];
        float s0 = q0[0] * k4.x + q0[1] * k4.y + q0[2] * k4.z + q0[3] * k4.w + q0[4] * k5;
        float s1 = q1[0] * k4.x + q1[1] * k4.y + q1[2] * k4.z + q1[3] * k4.w + q1[4] * k5;
        float e0 = __expf(s0);
        float e1 = __expf(s1);
        l0 += e0; l1 += e1;
        a0[0] += e0 * k4.x; a0[1] += e0 * k4.y; a0[2] += e0 * k4.z;
        a0[3] += e0 * k4.w; a0[4] += e0 * k5;
        a1[0] += e1 * k4.x; a1[1] += e1 * k4.y; a1[2] += e1 * k4.z;
        a1[3] += e1 * k4.w; a1[4] += e1 * k5;
    }
    float* p0 = part + ((size_t)blockIdx.x * NR + r0) * 8;
    float* p1 = part + ((size_t)blockIdx.x * NR + r1) * 8;
    p0[0] = a0[0]; p0[1] = a0[1]; p0[2] = a0[2]; p0[3] = a0[3]; p0[4] = a0[4]; p0[5] = l0;
    p1[0] = a1[0]; p1[1] = a1[1]; p1[2] = a1[2]; p1[3] = a1[3]; p1[4] = a1[4]; p1[5] = l1;
}

// ------------------------------- merge partials + aenet L3+L4 + outer ReLU
__global__ __launch_bounds__(256) void attn_merge_k(
    const float* __restrict__ part, const float* __restrict__ aw3,
    const float* __restrict__ ab3, const float* __restrict__ aw4,
    const float* __restrict__ ab4, float* __restrict__ S)
{
    __shared__ float w3s[50], b3s[10], w4s[1280], b4s[128];
    const int t = threadIdx.x;
    for (int i = t; i < 1280; i += 256) w4s[i] = aw4[i];
    if (t < 128) b4s[t] = ab4[t];
    if (t < 50)  w3s[t] = aw3[t];
    if (t < 10)  b3s[t] = ab3[t];
    __syncthreads();
    const int r = blockIdx.x * 256 + t;
    float acc[5] = {0, 0, 0, 0, 0};
    float l = 0.f;
    for (int c = 0; c < NCH; ++c) {
        const float* p = part + ((size_t)c * NR + r) * 8;
        float4 p4 = *(const float4*)p;
        acc[0] += p4.x; acc[1] += p4.y; acc[2] += p4.z; acc[3] += p4.w;
        acc[4] += p[4]; l += p[5];
    }
    const float inv = 1.f / l;
    float av[5];
    #pragma unroll
    for (int c = 0; c < 5; ++c) av[c] = acc[c] * inv;
    float v4[10];
    #pragma unroll
    for (int o = 0; o < 10; ++o) {
        float s = b3s[o];
        #pragma unroll
        for (int c = 0; c < 5; ++c) s += w3s[o * 5 + c] * av[c];
        v4[o] = fmaxf(s, 0.f);
    }
    float* srow = S + (size_t)r * CNN;
    for (int n = 0; n < CNN; n += 4) {
        float4 o4;
        float* op = (float*)&o4;
        #pragma unroll
        for (int q = 0; q < 4; ++q) {
            float s = b4s[n + q];
            #pragma unroll
            for (int o = 0; o < 10; ++o) s += w4s[(n + q) * 10 + o] * v4[o];
            op[q] = fmaxf(s, 0.f);
        }
        *(float4*)(srow + n) = o4;
    }
}

// --------------------------------------------------------------- launcher
extern "C" void kernel_launch(void* const* d_in, const int* in_sizes, int n_in,
                              void* d_out, int out_size, void* d_ws, size_t ws_size,
                              hipStream_t stream)
{
    (void)in_sizes; (void)n_in; (void)out_size; (void)ws_size;
    const float* H     = (const float*)d_in[0];
    const float* alpha = (const float*)d_in[1];
    const float* gamma = (const float*)d_in[2];
    const float* beta  = (const float*)d_in[3];
    const float* w1    = (const float*)d_in[4];
    const float* b1    = (const float*)d_in[5];
    const float* wdt   = (const float*)d_in[6];
    const float* bdt   = (const float*)d_in[7];
    const float* wdtd  = (const float*)d_in[8];
    const float* bdtd  = (const float*)d_in[9];
    const float* aw1   = (const float*)d_in[10];
    const float* ab1   = (const float*)d_in[11];
    const float* aw2   = (const float*)d_in[12];
    const float* ab2   = (const float*)d_in[13];
    const float* aw3   = (const float*)d_in[14];
    const float* ab3   = (const float*)d_in[15];
    const float* aw4   = (const float*)d_in[16];
    const float* ab4   = (const float*)d_in[17];

    float* ws   = (float*)d_ws;
    float* V    = ws + OFF_V;
    float* S    = ws + OFF_S;
    float* DTH  = ws + OFF_DTH;
    float* V2   = ws + OFF_V2;
    float* part = ws + OFF_PART;

    float* outV  = (float*)d_out;
    float* outHR = outV + (size_t)NR * CNN;

    bn_stats_k<<<CIN, 256, 0, stream>>>(H, gamma, beta, ws);
    gemm_bn_k<<<dim3(NR / 64, 4), 256, 0, stream>>>(H, w1, b1, wdt, bdt, ws, V, DTH);

    for (int it = 0; it < 3; ++it) {
        aenet_l12_k<<<NR / 256, 256, 0, stream>>>(V, aw1, ab1, aw2, ab2, V2);
        attn_partial_k<<<dim3(NCH, NR / 512), 256, 0, stream>>>(V2, part);
        attn_merge_k<<<NR / 256, 256, 0, stream>>>(part, aw3, ab3, aw4, ab4, S);
        gemm_iter_k<<<dim3(NR / 64, 2), 256, 0, stream>>>(
            DTH, S, alpha, wdtd, bdtd, V, (it == 2) ? outV : (float*)nullptr);
    }
    gemm_hr_k<<<dim3(NR / 64, 4), 256, 0, stream>>>(V, wdt, outHR);
}

// Round 3
// 212.336 us; speedup vs baseline: 1.4756x; 1.4756x over previous
//
#include <hip/hip_runtime.h>
#include <hip/hip_bf16.h>

#define NR   8192
#define CIN  200
#define CNN  128
#define NCH  32
#define JC   (NR / NCH)   // 256
#define BN_EPS 1e-5f

// ws float offsets
#define OFF_SCALE  0
#define OFF_SHIFT  256
#define OFF_BNPART 512                       // 128 blocks * 400
#define OFF_DTH    (OFF_BNPART + 128 * 400)
#define OFF_V2     (OFF_DTH + NR * CNN)
#define OFF_V4     (OFF_V2 + NR * 8)         // v4T [10][NR]
#define OFF_PART   (OFF_V4 + 10 * NR)

// ------------------------------------------------ BN pass 1: row-block partials
__global__ __launch_bounds__(256) void bn1_k(
    const float* __restrict__ H, float* __restrict__ ws)
{
    const int t = threadIdx.x;
    if (t >= CIN) return;
    const int r0 = blockIdx.x * 64;
    const float* p = H + (size_t)r0 * CIN + t;
    float s = 0.f, q = 0.f;
    #pragma unroll 4
    for (int r = 0; r < 64; ++r) {
        float v = p[(size_t)r * CIN];
        s += v; q += v * v;
    }
    float* o = ws + OFF_BNPART + blockIdx.x * 400;
    o[t] = s; o[200 + t] = q;
}

// ------------------------------------------------ BN pass 2: finalize scale/shift
__global__ __launch_bounds__(64) void bn2_k(
    float* __restrict__ ws, const float* __restrict__ gamma,
    const float* __restrict__ beta)
{
    const int c = blockIdx.x;   // 0..199
    const int t = threadIdx.x;  // 64
    float s = 0.f, q = 0.f;
    for (int b = t; b < 128; b += 64) {
        const float* p = ws + OFF_BNPART + b * 400;
        s += p[c]; q += p[200 + c];
    }
    #pragma unroll
    for (int off = 32; off >= 1; off >>= 1) {
        s += __shfl_down(s, off);
        q += __shfl_down(q, off);
    }
    if (t == 0) {
        float mu  = s * (1.f / NR);
        float var = q * (1.f / NR) - mu * mu;
        float sc  = rsqrtf(var + BN_EPS) * gamma[c];
        ws[OFF_SCALE + c] = sc;
        ws[OFF_SHIFT + c] = beta[c] - mu * sc;
    }
}

// ---------------------------------------------------------------------------
// gemm_bn: y==0 -> V0 tile (relu, +l12 epilogue -> V2), y==1 -> DTH
// BM=32, BN=128, K=200, grid (256,2)
__global__ __launch_bounds__(256) void gemm_bn_k(
    const float* __restrict__ H, const float* __restrict__ w1,
    const float* __restrict__ b1, const float* __restrict__ wdt,
    const float* __restrict__ bdt,
    const float* __restrict__ aw1, const float* __restrict__ ab1,
    const float* __restrict__ aw2, const float* __restrict__ ab2,
    const float* __restrict__ ws, float* __restrict__ DTH,
    float* __restrict__ V2)
{
    __shared__ float As[8][36];
    __shared__ float Bs[8][136];
    __shared__ float scs[200], shs[200];
    __shared__ float biass[128];
    __shared__ float aw1s[1280];
    __shared__ float aw2s[52], ab1s[12], ab2s[8];
    __shared__ float Ct[32][133];
    __shared__ float v1s[32][12];

    const int t  = threadIdx.x;
    const int m0 = blockIdx.x * 32;
    const bool isV = (blockIdx.y == 0);

    if (t < 200) { scs[t] = ws[OFF_SCALE + t]; shs[t] = ws[OFF_SHIFT + t]; }
    if (t < 128) biass[t] = isV ? b1[t] : bdt[t];
    if (isV) {
        for (int i = t; i < 1280; i += 256) aw1s[i] = aw1[i];
        if (t < 50) aw2s[t] = aw2[t];
        if (t < 10) ab1s[t] = ab1[t];
        if (t < 5)  ab2s[t] = ab2[t];
    }
    const int am = t >> 3, ak = t & 7;
    const int bn_ = t >> 1, bk4 = (t & 1) * 4;
    const float* brow = (isV ? w1 : wdt) + (size_t)bn_ * CIN + bk4;
    const float* arow = H + (size_t)(m0 + am) * CIN + ak;
    const int tx = t & 31, ty = t >> 5;
    float acc[4][4] = {};
    __syncthreads();

    for (int k0 = 0; k0 < CIN; k0 += 8) {
        const int k = k0 + ak;
        float  aval = arow[k0] * scs[k] + shs[k];
        float4 bv   = *(const float4*)(brow + k0);
        __syncthreads();
        As[ak][am] = aval;
        Bs[bk4 + 0][bn_] = bv.x; Bs[bk4 + 1][bn_] = bv.y;
        Bs[bk4 + 2][bn_] = bv.z; Bs[bk4 + 3][bn_] = bv.w;
        __syncthreads();
        #pragma unroll
        for (int kk = 0; kk < 8; ++kk) {
            float4 av  = *(const float4*)&As[kk][ty * 4];
            float4 bv4 = *(const float4*)&Bs[kk][tx * 4];
            float a[4] = {av.x, av.y, av.z, av.w};
            float b[4] = {bv4.x, bv4.y, bv4.z, bv4.w};
            #pragma unroll
            for (int i = 0; i < 4; ++i)
                #pragma unroll
                for (int j = 0; j < 4; ++j)
                    acc[i][j] += a[i] * b[j];
        }
    }

    if (isV) {
        #pragma unroll
        for (int i = 0; i < 4; ++i) {
            const int m = ty * 4 + i;
            #pragma unroll
            for (int j = 0; j < 4; ++j) {
                const int n = tx * 4 + j;
                Ct[m][n] = fmaxf(acc[i][j] + biass[n], 0.f);
            }
        }
        __syncthreads();
        for (int o = ty; o < 10; o += 8) {
            const int row = tx;
            float s = ab1s[o];
            const float* wr = &aw1s[o * 128];
            #pragma unroll 8
            for (int k = 0; k < 128; ++k) s += Ct[row][k] * wr[k];
            v1s[row][o] = fmaxf(s, 0.f);
        }
        __syncthreads();
        if (t < 32) {
            float vv[10];
            #pragma unroll
            for (int o = 0; o < 10; ++o) vv[o] = v1s[t][o];
            #pragma unroll
            for (int p = 0; p < 5; ++p) {
                float s = ab2s[p];
                #pragma unroll
                for (int o = 0; o < 10; ++o) s += aw2s[p * 10 + o] * vv[o];
                V2[(size_t)(m0 + t) * 8 + p] = fmaxf(s, 0.f);
            }
        }
    } else {
        #pragma unroll
        for (int i = 0; i < 4; ++i) {
            const int m = m0 + ty * 4 + i;
            float4 ov = make_float4(acc[i][0] + biass[tx * 4 + 0],
                                    acc[i][1] + biass[tx * 4 + 1],
                                    acc[i][2] + biass[tx * 4 + 2],
                                    acc[i][3] + biass[tx * 4 + 3]);
            *(float4*)(DTH + (size_t)m * CNN + tx * 4) = ov;
        }
    }
}

// ---------------------------------------------------------------------------
// iter GEMM: A[m,k] = DTH[m,k] + alpha*relu(L4(v4)[m,k]); C = relu(A@wdtd^T+b)
// epilogue: l12 -> V2  (or write outV when last). BM=32,BN=128,K=128,grid 256
__global__ __launch_bounds__(256) void iter_k(
    const float* __restrict__ DTH, const float* __restrict__ v4T,
    const float* __restrict__ alpha_p,
    const float* __restrict__ wdtd, const float* __restrict__ bdtd,
    const float* __restrict__ aw4, const float* __restrict__ ab4,
    const float* __restrict__ aw1, const float* __restrict__ ab1,
    const float* __restrict__ aw2, const float* __restrict__ ab2,
    float* __restrict__ V2, float* __restrict__ outV)
{
    __shared__ float As[8][36];
    __shared__ float Bs[8][136];
    __shared__ float w4s[1280];
    __shared__ float b4s[128], bds[128];
    __shared__ float aw1s[1280];
    __shared__ float aw2s[52], ab1s[12], ab2s[8];
    __shared__ float Ct[32][133];
    __shared__ float v1s[32][12];

    const int t  = threadIdx.x;
    const int m0 = blockIdx.x * 32;
    const bool last = (outV != nullptr);

    for (int i = t; i < 1280; i += 256) { w4s[i] = aw4[i]; aw1s[i] = aw1[i]; }
    if (t < 128) { b4s[t] = ab4[t]; bds[t] = bdtd[t]; }
    if (t < 50) aw2s[t] = aw2[t];
    if (t < 10) ab1s[t] = ab1[t];
    if (t < 5)  ab2s[t] = ab2[t];

    const float alpha = alpha_p[0];
    const int am = t >> 3, ak = t & 7;
    float v4r[10];
    #pragma unroll
    for (int o = 0; o < 10; ++o) v4r[o] = v4T[o * NR + m0 + am];
    const int bn_ = t >> 1, bk4 = (t & 1) * 4;
    const float* brow = wdtd + (size_t)bn_ * CNN + bk4;
    const float* arow = DTH + (size_t)(m0 + am) * CNN + ak;
    const int tx = t & 31, ty = t >> 5;
    float acc[4][4] = {};
    __syncthreads();

    for (int k0 = 0; k0 < CNN; k0 += 8) {
        const int k = k0 + ak;
        float pre = b4s[k];
        #pragma unroll
        for (int o = 0; o < 10; ++o) pre += w4s[k * 10 + o] * v4r[o];
        float  aval = arow[k0] + alpha * fmaxf(pre, 0.f);
        float4 bv   = *(const float4*)(brow + k0);
        __syncthreads();
        As[ak][am] = aval;
        Bs[bk4 + 0][bn_] = bv.x; Bs[bk4 + 1][bn_] = bv.y;
        Bs[bk4 + 2][bn_] = bv.z; Bs[bk4 + 3][bn_] = bv.w;
        __syncthreads();
        #pragma unroll
        for (int kk = 0; kk < 8; ++kk) {
            float4 av  = *(const float4*)&As[kk][ty * 4];
            float4 bv4 = *(const float4*)&Bs[kk][tx * 4];
            float a[4] = {av.x, av.y, av.z, av.w};
            float b[4] = {bv4.x, bv4.y, bv4.z, bv4.w};
            #pragma unroll
            for (int i = 0; i < 4; ++i)
                #pragma unroll
                for (int j = 0; j < 4; ++j)
                    acc[i][j] += a[i] * b[j];
        }
    }

    if (!last) {
        #pragma unroll
        for (int i = 0; i < 4; ++i) {
            const int m = ty * 4 + i;
            #pragma unroll
            for (int j = 0; j < 4; ++j) {
                const int n = tx * 4 + j;
                Ct[m][n] = fmaxf(acc[i][j] + bds[n], 0.f);
            }
        }
        __syncthreads();
        for (int o = ty; o < 10; o += 8) {
            const int row = tx;
            float s = ab1s[o];
            const float* wr = &aw1s[o * 128];
            #pragma unroll 8
            for (int k = 0; k < 128; ++k) s += Ct[row][k] * wr[k];
            v1s[row][o] = fmaxf(s, 0.f);
        }
        __syncthreads();
        if (t < 32) {
            float vv[10];
            #pragma unroll
            for (int o = 0; o < 10; ++o) vv[o] = v1s[t][o];
            #pragma unroll
            for (int p = 0; p < 5; ++p) {
                float s = ab2s[p];
                #pragma unroll
                for (int o = 0; o < 10; ++o) s += aw2s[p * 10 + o] * vv[o];
                V2[(size_t)(m0 + t) * 8 + p] = fmaxf(s, 0.f);
            }
        }
    } else {
        #pragma unroll
        for (int i = 0; i < 4; ++i) {
            const int m = m0 + ty * 4 + i;
            float4 ov = make_float4(fmaxf(acc[i][0] + bds[tx * 4 + 0], 0.f),
                                    fmaxf(acc[i][1] + bds[tx * 4 + 1], 0.f),
                                    fmaxf(acc[i][2] + bds[tx * 4 + 2], 0.f),
                                    fmaxf(acc[i][3] + bds[tx * 4 + 3], 0.f));
            *(float4*)(outV + (size_t)m * CNN + tx * 4) = ov;
        }
    }
}

// ---------------------------------------- attention partials (unnormalized)
__global__ __launch_bounds__(256) void attn_partial_k(
    const float* __restrict__ V2, float* __restrict__ part)
{
    __shared__ float Ks[JC][8];
    const int t  = threadIdx.x;
    const int j0 = blockIdx.x * JC;
    {
        const float4* src = (const float4*)(V2 + (size_t)j0 * 8);
        float4* dst = (float4*)&Ks[0][0];
        #pragma unroll
        for (int i = 0; i < (JC * 2) / 256; ++i)
            dst[t + i * 256] = src[t + i * 256];
    }
    __syncthreads();
    const int r0 = blockIdx.y * 512 + t;
    const int r1 = r0 + 256;
    float4 q0a = *(const float4*)(V2 + (size_t)r0 * 8);
    float  q0e = V2[(size_t)r0 * 8 + 4];
    float4 q1a = *(const float4*)(V2 + (size_t)r1 * 8);
    float  q1e = V2[(size_t)r1 * 8 + 4];
    float l0 = 0.f, l1 = 0.f;
    float a0[5] = {0, 0, 0, 0, 0}, a1[5] = {0, 0, 0, 0, 0};
    #pragma unroll 4
    for (int jj = 0; jj < JC; ++jj) {
        float4 k4 = *(const float4*)&Ks[jj][0];
        float  k5 = Ks[jj][4];
        float s0 = q0a.x * k4.x + q0a.y * k4.y + q0a.z * k4.z + q0a.w * k4.w + q0e * k5;
        float s1 = q1a.x * k4.x + q1a.y * k4.y + q1a.z * k4.z + q1a.w * k4.w + q1e * k5;
        float e0 = __expf(s0);
        float e1 = __expf(s1);
        l0 += e0; l1 += e1;
        a0[0] += e0 * k4.x; a0[1] += e0 * k4.y; a0[2] += e0 * k4.z;
        a0[3] += e0 * k4.w; a0[4] += e0 * k5;
        a1[0] += e1 * k4.x; a1[1] += e1 * k4.y; a1[2] += e1 * k4.z;
        a1[3] += e1 * k4.w; a1[4] += e1 * k5;
    }
    float* p0 = part + ((size_t)blockIdx.x * NR + r0) * 8;
    float* p1 = part + ((size_t)blockIdx.x * NR + r1) * 8;
    *(float4*)p0       = make_float4(a0[0], a0[1], a0[2], a0[3]);
    *(float2*)(p0 + 4) = make_float2(a0[4], l0);
    *(float4*)p1       = make_float4(a1[0], a1[1], a1[2], a1[3]);
    *(float2*)(p1 + 4) = make_float2(a1[4], l1);
}

// ------------------------------ merge partials + softmax-div + L3 -> v4T
__global__ __launch_bounds__(256) void merge_k(
    const float* __restrict__ part, const float* __restrict__ aw3,
    const float* __restrict__ ab3, float* __restrict__ v4T)
{
    __shared__ float w3s[52], b3s[12];
    const int t = threadIdx.x;
    if (t < 50) w3s[t] = aw3[t];
    if (t < 10) b3s[t] = ab3[t];
    __syncthreads();
    const int r = blockIdx.x * 256 + t;
    float a0 = 0.f, a1 = 0.f, a2 = 0.f, a3 = 0.f, a4 = 0.f, l = 0.f;
    for (int c = 0; c < NCH; ++c) {
        const float* p = part + ((size_t)c * NR + r) * 8;
        float4 x = *(const float4*)p;
        float2 y = *(const float2*)(p + 4);
        a0 += x.x; a1 += x.y; a2 += x.z; a3 += x.w; a4 += y.x; l += y.y;
    }
    const float inv = 1.f / l;
    float av[5] = {a0 * inv, a1 * inv, a2 * inv, a3 * inv, a4 * inv};
    #pragma unroll
    for (int o = 0; o < 10; ++o) {
        float s = b3s[o];
        #pragma unroll
        for (int c = 0; c < 5; ++c) s += w3s[o * 5 + c] * av[c];
        v4T[o * NR + r] = fmaxf(s, 0.f);
    }
}

// ------------------------------------------------------ H_R = V @ wdt (f32)
__global__ __launch_bounds__(256) void gemm_hr_k(
    const float* __restrict__ Vf, const float* __restrict__ wdt,
    float* __restrict__ out)
{
    __shared__ float As[8][68];
    __shared__ float Bs[8][68];
    const int t  = threadIdx.x;
    const int m0 = blockIdx.x * 64;
    const int n0 = blockIdx.y * 64;
    const int tx = t & 15, ty = t >> 4;
    const int lm = t >> 2;
    const int lk = (t & 3) * 2;
    const int bkk = t >> 5;
    const int bnn = (t & 31) * 2;
    float acc[4][4] = {};
    for (int k0 = 0; k0 < CNN; k0 += 8) {
        float2 a2 = *(const float2*)(Vf + (size_t)(m0 + lm) * CNN + k0 + lk);
        float2 w2 = make_float2(0.f, 0.f);
        if (n0 + bnn < CIN)
            w2 = *(const float2*)(wdt + (size_t)(k0 + bkk) * CIN + n0 + bnn);
        __syncthreads();
        As[lk][lm]     = a2.x;
        As[lk + 1][lm] = a2.y;
        Bs[bkk][bnn]     = w2.x;
        Bs[bkk][bnn + 1] = w2.y;
        __syncthreads();
        #pragma unroll
        for (int kk = 0; kk < 8; ++kk) {
            float a[4], b[4];
            #pragma unroll
            for (int i = 0; i < 4; ++i) a[i] = As[kk][ty * 4 + i];
            #pragma unroll
            for (int j = 0; j < 4; ++j) b[j] = Bs[kk][tx * 4 + j];
            #pragma unroll
            for (int i = 0; i < 4; ++i)
                #pragma unroll
                for (int j = 0; j < 4; ++j)
                    acc[i][j] += a[i] * b[j];
        }
    }
    #pragma unroll
    for (int i = 0; i < 4; ++i) {
        const int m = m0 + ty * 4 + i;
        #pragma unroll
        for (int j = 0; j < 4; ++j) {
            const int n = n0 + tx * 4 + j;
            if (n < CIN) out[(size_t)m * CIN + n] = acc[i][j];
        }
    }
}

// --------------------------------------------------------------- launcher
extern "C" void kernel_launch(void* const* d_in, const int* in_sizes, int n_in,
                              void* d_out, int out_size, void* d_ws, size_t ws_size,
                              hipStream_t stream)
{
    (void)in_sizes; (void)n_in; (void)out_size; (void)ws_size;
    const float* H     = (const float*)d_in[0];
    const float* alpha = (const float*)d_in[1];
    const float* gamma = (const float*)d_in[2];
    const float* beta  = (const float*)d_in[3];
    const float* w1    = (const float*)d_in[4];
    const float* b1    = (const float*)d_in[5];
    const float* wdt   = (const float*)d_in[6];
    const float* bdt   = (const float*)d_in[7];
    const float* wdtd  = (const float*)d_in[8];
    const float* bdtd  = (const float*)d_in[9];
    const float* aw1   = (const float*)d_in[10];
    const float* ab1   = (const float*)d_in[11];
    const float* aw2   = (const float*)d_in[12];
    const float* ab2   = (const float*)d_in[13];
    const float* aw3   = (const float*)d_in[14];
    const float* ab3   = (const float*)d_in[15];
    const float* aw4   = (const float*)d_in[16];
    const float* ab4   = (const float*)d_in[17];

    float* ws   = (float*)d_ws;
    float* DTH  = ws + OFF_DTH;
    float* V2   = ws + OFF_V2;
    float* v4T  = ws + OFF_V4;
    float* part = ws + OFF_PART;

    float* outV  = (float*)d_out;
    float* outHR = outV + (size_t)NR * CNN;

    bn1_k<<<128, 256, 0, stream>>>(H, ws);
    bn2_k<<<CIN, 64, 0, stream>>>(ws, gamma, beta);
    gemm_bn_k<<<dim3(256, 2), 256, 0, stream>>>(H, w1, b1, wdt, bdt,
                                                aw1, ab1, aw2, ab2, ws, DTH, V2);
    for (int it = 0; it < 3; ++it) {
        attn_partial_k<<<dim3(NCH, NR / 512), 256, 0, stream>>>(V2, part);
        merge_k<<<NR / 256, 256, 0, stream>>>(part, aw3, ab3, v4T);
        iter_k<<<256, 256, 0, stream>>>(DTH, v4T, alpha, wdtd, bdtd,
                                        aw4, ab4, aw1, ab1, aw2, ab2,
                                        V2, (it == 2) ? outV : (float*)nullptr);
    }
    gemm_hr_k<<<dim3(128, 4), 256, 0, stream>>>(outV, wdt, outHR);
}